// Round 13
// baseline (321.721 us; speedup 1.0000x reference)
//
#include <hip/hip_runtime.h>
#include <stdint.h>

// Problem: B=2, S=2048, D=1024, H=16, dh=64
// Inputs fp32, OUTPUT fp32. Internals bf16 (threshold has bf16 floor).
#define SEQ    2048
#define DMODEL 1024

typedef __bf16 bf16x8 __attribute__((ext_vector_type(8)));
typedef float  f32x4  __attribute__((ext_vector_type(4)));

typedef __attribute__((address_space(1))) const void CGV;  // global
typedef __attribute__((address_space(3))) void LDSV;       // LDS

__device__ __forceinline__ void load_lds16(const void* g, void* l) {
    __builtin_amdgcn_global_load_lds((CGV*)g, (LDSV*)l, 16, 0, 0);
}

// native v_exp_f32 (llvm.exp2.f32 is legal on amdgcn)
__device__ __forceinline__ float fast_exp2(float x) { return __builtin_exp2f(x); }

// ---------------------------------------------------------------------------
// prep_kernel: fuses {Wqkv transpose, Wout transpose, src f32->bf16 convert}
// into ONE launch.  blocks [0,3072): Wqkv; [3072,4096): Wout; [4096,6144): src.
// ---------------------------------------------------------------------------
__global__ __launch_bounds__(256)
void prep_kernel(const float* __restrict__ src, const float* __restrict__ Wqkv,
                 const float* __restrict__ Wout, __bf16* __restrict__ SrcBf,
                 __bf16* __restrict__ Wqkv_t, __bf16* __restrict__ Wout_t)
{
    __shared__ float tile[32][33];
    const int id = blockIdx.x;
    const int t  = threadIdx.x;
    if (id < 4096) {
        const float* in;
        __bf16* out;
        int R, C, bx, by;
        if (id < 3072) { in = Wqkv; out = Wqkv_t; R = 1024; C = 3072; bx = id % 96; by = id / 96; }
        else           { int l = id - 3072; in = Wout; out = Wout_t; R = 1024; C = 1024; bx = l & 31; by = l >> 5; }
        const int tx = t & 31, ty = t >> 5;
        const int c0 = bx * 32, r0 = by * 32;
#pragma unroll
        for (int i = 0; i < 4; ++i)
            tile[ty + i * 8][tx] = in[(size_t)(r0 + ty + i * 8) * C + c0 + tx];
        __syncthreads();
#pragma unroll
        for (int i = 0; i < 4; ++i)
            out[(size_t)(c0 + ty + i * 8) * R + r0 + tx] = (__bf16)tile[tx][ty + i * 8];
    } else {
        const int i = ((id - 4096) * 256 + t) * 8;
        float4 a = *(const float4*)(src + i);
        float4 b = *(const float4*)(src + i + 4);
        __bf16 tmp[8] = { (__bf16)a.x, (__bf16)a.y, (__bf16)a.z, (__bf16)a.w,
                          (__bf16)b.x, (__bf16)b.y, (__bf16)b.z, (__bf16)b.w };
        *(uint4*)(SrcBf + i) = *(uint4*)tmp;
    }
}

// ---------------------------------------------------------------------------
// GEMM v12 (unchanged): m97 structure + depth-2 pipeline + fused V^T store.
// ---------------------------------------------------------------------------
template<int BM, int BN>
__global__ __launch_bounds__(256)
void gemm_kernel(const __bf16* __restrict__ A, const __bf16* __restrict__ Bt,
                 const float* __restrict__ bias,
                 __bf16* __restrict__ Cq, __bf16* __restrict__ Ck,
                 __bf16* __restrict__ Cvt, float* __restrict__ Cplain,
                 int K, int N, int mode)
{
    __shared__ __attribute__((aligned(16))) __bf16 As[3][BM][32];
    __shared__ __attribute__((aligned(16))) __bf16 Bs[3][BN][32];

    const int t    = threadIdx.x;
    const int wave = __builtin_amdgcn_readfirstlane(t >> 6);
    const int lane = t & 63;
    const int l15  = lane & 15;
    const int quad = lane >> 4;
    const int wm   = (wave >> 1) * (BM / 2);
    const int wn   = (wave & 1) * (BN / 2);
    const int m0   = blockIdx.y * BM;
    const int n0   = blockIdx.x * BN;

    const int arow  = lane >> 2;        // 0..15 within a 16-row slab
    const int akoff = (lane & 3) * 8;   // lane covers 8 bf16 of k

    constexpr int MI  = BM / 32;        // 16-row blocks per wave (M)
    constexpr int NI  = BN / 32;        // 16-col blocks per wave (N)
    constexpr int NLD = BM / 64 + BN / 64;  // gll per wave per stage

    f32x4 acc[MI][NI] = {};

#define GSTAGE(buf, kk)                                                        \
    {                                                                          \
        _Pragma("unroll")                                                      \
        for (int p = 0; p < BM / 64; ++p) {                                    \
            int slab = (wave * (BM / 64) + p) * 16;                            \
            load_lds16(A  + (size_t)(m0 + slab + arow) * K + (kk) + akoff,     \
                       &As[buf][slab][0]);                                     \
        }                                                                      \
        _Pragma("unroll")                                                      \
        for (int p = 0; p < BN / 64; ++p) {                                    \
            int slab = (wave * (BN / 64) + p) * 16;                            \
            load_lds16(Bt + (size_t)(n0 + slab + arow) * K + (kk) + akoff,     \
                       &Bs[buf][slab][0]);                                     \
        }                                                                      \
    }

    // prologue: two stages in flight
    GSTAGE(0, 0);
    GSTAGE(1, 32);
    int cur = 0;
#pragma unroll 2
    for (int k0 = 0; k0 < K; k0 += 32) {
        // drain ONLY the oldest stage; the next stage rides (T4 counted wait).
        if (k0 + 64 < K) {
            if constexpr (NLD == 4) asm volatile("s_waitcnt vmcnt(4)" ::: "memory");
            else                    asm volatile("s_waitcnt vmcnt(3)" ::: "memory");
        } else {
            asm volatile("s_waitcnt vmcnt(0)" ::: "memory");   // tail
        }
        __builtin_amdgcn_s_barrier();
        __builtin_amdgcn_sched_barrier(0);
        if (k0 + 64 < K) {
            int c2 = cur + 2; if (c2 >= 3) c2 -= 3;
            GSTAGE(c2, k0 + 64);
        }
        __builtin_amdgcn_sched_barrier(0);

        bf16x8 af[MI], bfr[NI];
#pragma unroll
        for (int mi = 0; mi < MI; ++mi)
            af[mi] = *(const bf16x8*)(&As[cur][wm + mi * 16 + l15][quad * 8]);
#pragma unroll
        for (int ni = 0; ni < NI; ++ni)
            bfr[ni] = *(const bf16x8*)(&Bs[cur][wn + ni * 16 + l15][quad * 8]);
#pragma unroll
        for (int mi = 0; mi < MI; ++mi)
#pragma unroll
            for (int ni = 0; ni < NI; ++ni)
                acc[mi][ni] = __builtin_amdgcn_mfma_f32_16x16x32_bf16(
                    af[mi], bfr[ni], acc[mi][ni], 0, 0, 0);
        ++cur; if (cur == 3) cur = 0;
    }
#undef GSTAGE

    // epilogue: C/D layout col=lane&15, row=quad*4+reg
#pragma unroll
    for (int mi = 0; mi < MI; ++mi) {
        int rowb = m0 + wm + mi * 16 + quad * 4;
#pragma unroll
        for (int ni = 0; ni < NI; ++ni) {
            int col = n0 + wn + ni * 16 + l15;
            float bia = bias[col];
            float v4[4];
#pragma unroll
            for (int r = 0; r < 4; ++r)
                v4[r] = acc[mi][ni][r] + bia;
            if (mode == 0) {
                int part = col >> 10;        // wave-uniform per (ni)
                int rem  = col & 1023;
                int h = rem >> 6;
                int d = rem & 63;
                int b  = rowb >> 11;         // constant across r (rowb mult of 4)
                int sb = rowb & 2047;
                if (part == 2) {
                    // V^T fused: 4 consecutive s at fixed d -> one 8B store
                    union { __bf16 hh[4]; uint2 u; } pk;
                    pk.hh[0] = (__bf16)v4[0];
                    pk.hh[1] = (__bf16)v4[1];
                    pk.hh[2] = (__bf16)v4[2];
                    pk.hh[3] = (__bf16)v4[3];
                    *(uint2*)(Cvt + ((size_t)(b * 16 + h) * 64 + d) * SEQ + sb) = pk.u;
                } else {
                    __bf16* dst = (part == 0) ? Cq : Ck;
#pragma unroll
                    for (int r = 0; r < 4; ++r)
                        dst[(((size_t)(b * 16 + h)) * SEQ + sb + r) * 64 + d] = (__bf16)v4[r];
                }
            } else {
#pragma unroll
                for (int r = 0; r < 4; ++r)
                    Cplain[(size_t)(rowb + r) * N + col] = v4[r];   // fp32 output
            }
        }
    }
}

// ---------------------------------------------------------------------------
// MFMA flash attention v13 = v9 pipeline with Kt SINGLE-buffered (LDS diet):
//   Kt is dead after QK -> stage K(t+1) into the SAME buffer after a post-QK
//   barrier (gll writes land async, published by next tile-top vmcnt(0)+bar).
//   LDS 40960 -> 32768 (Kt 8K + Vt dbuf 16K + Ps 8K) => 4-5 blocks/CU
//   (was 3: 40960x4 = exactly 163840, runtime reserve pushed us to 3).
//   Cost: +1 s_barrier per tile. Everything else byte-identical to v9.
// grid (B*H=32, S/64=32) x 256 thr.
// ---------------------------------------------------------------------------
__global__ __launch_bounds__(256, 5)
void attn_kernel(const __bf16* __restrict__ Q, const __bf16* __restrict__ Kb,
                 const __bf16* __restrict__ Vtg, const float* __restrict__ mask,
                 __bf16* __restrict__ Out)
{
    __shared__ __attribute__((aligned(16))) __bf16 Kt[64 * 64];    // [key][d] swz, SINGLE
    __shared__ __attribute__((aligned(16))) __bf16 Vt[2][64 * 64]; // [d][key] swz
    __shared__ __attribute__((aligned(16))) __bf16 Ps[4][16 * 64]; // [q][key] swz

    const int t    = threadIdx.x;
    const int wave = __builtin_amdgcn_readfirstlane(t >> 6);
    const int lane = t & 63;
    const int l15  = lane & 15;
    const int quad = lane >> 4;
    const int swq  = lane & 7;                  // == l15 & 7
    const int bh   = blockIdx.x;
    const int b    = bh >> 4;
    const int h    = bh & 15;
    const int q0   = blockIdx.y * 64 + wave * 16;

    const float C1 = 0.180336880f;    // 0.125 * log2(e)
    const float C2 = 14426.9502f;     // 1e4  * log2(e)

    const __bf16* Qp  = Q   + (size_t)bh * SEQ * 64;
    const __bf16* Kp  = Kb  + (size_t)bh * SEQ * 64;
    const __bf16* Vtp = Vtg + (size_t)bh * 64 * SEQ;   // [d][s]
    const float*  Mrow = mask + (size_t)b * SEQ * SEQ + (size_t)(q0 + l15) * SEQ + quad * 4;

    // ---- stage-source lane constants (v5-verified swizzle family) ----
    const int ch  = wave * 2;
    const int rw0 = ch * 8 + (lane >> 3);
    const int swz = ((lane & 7) ^ (lane >> 3)) * 8;
    const __bf16* kS0 = Kp  + (size_t)rw0 * 64 + swz;
    const __bf16* kS1 = Kp  + (size_t)(rw0 + 8) * 64 + swz;
    const __bf16* vS0 = Vtp + (size_t)rw0 * SEQ + swz;
    const __bf16* vS1 = Vtp + (size_t)(rw0 + 8) * SEQ + swz;

    bf16x8 qf[2];
#pragma unroll
    for (int ks = 0; ks < 2; ++ks)
        qf[ks] = *(const bf16x8*)(Qp + (size_t)(q0 + l15) * 64 + ks * 32 + quad * 8);

    f32x4 oacc[4] = {};
    float mrun = -1e30f, lrun = 0.f;   // scalar state: this lane's q = q0+l15

    // ---- prologue: stage K(0)->Kt, V(0)->Vt[0]; mask tile 0 into regs ----
    load_lds16(kS0, &Kt[ch * 512]);
    load_lds16(kS1, &Kt[(ch + 1) * 512]);
    load_lds16(vS0, &Vt[0][ch * 512]);
    load_lds16(vS1, &Vt[0][(ch + 1) * 512]);
    f32x4 mk[4];
#pragma unroll
    for (int nb = 0; nb < 4; ++nb)
        mk[nb] = *(const f32x4*)(Mrow + nb * 16);

    const char* PsW = (const char*)&Ps[wave][0] + l15 * 128;

#pragma unroll 2
    for (int tt = 0; tt < SEQ / 64; ++tt) {
        const int key0 = tt * 64;
        const int keyn = (key0 + 64 <= SEQ - 64) ? key0 + 64 : SEQ - 64; // clamp
        const int cur  = tt & 1;
        const char* vcur = (const char*)&Vt[cur][0];
        __bf16* vnxt = &Vt[cur ^ 1][0];

        // --- top-of-tile: all staged loads done; publish Kt + Vt[cur] ---
        asm volatile("s_waitcnt vmcnt(0)" ::: "memory");
        __builtin_amdgcn_s_barrier();
        __builtin_amdgcn_sched_barrier(0);

        // --- issue V(t+1) stage (async; drained at NEXT tile's top) ---
        load_lds16(vS0 + keyn, vnxt + ch * 512);
        load_lds16(vS1 + keyn, vnxt + (ch + 1) * 512);
        __builtin_amdgcn_sched_barrier(0);

        // --- QK from Kt (S^T: rows=keys on l15, q via qf) ---
        f32x4 sa[4];
#pragma unroll
        for (int nb = 0; nb < 4; ++nb) {
            const char* kb = (const char*)Kt + (nb * 16 + l15) * 128;
            bf16x8 kf0 = *(const bf16x8*)(kb + (((quad) ^ swq) << 4));
            bf16x8 kf1 = *(const bf16x8*)(kb + (((4 + quad) ^ swq) << 4));
            f32x4 z = {};
            z = __builtin_amdgcn_mfma_f32_16x16x32_bf16(kf0, qf[0], z, 0, 0, 0);
            z = __builtin_amdgcn_mfma_f32_16x16x32_bf16(kf1, qf[1], z, 0, 0, 0);
            sa[nb] = z;
        }
        __builtin_amdgcn_sched_barrier(0);

        // --- barrier #2: all waves' QK reads of Kt complete -> Kt reusable ---
        __builtin_amdgcn_s_barrier();
        __builtin_amdgcn_sched_barrier(0);

        // --- issue K(t+1) stage into Kt (published at next tile top) ---
        load_lds16(kS0 + (size_t)keyn * 64, &Kt[ch * 512]);
        load_lds16(kS1 + (size_t)keyn * 64, &Kt[(ch + 1) * 512]);
        __builtin_amdgcn_sched_barrier(0);

        // --- mask + scale in log2 domain (consume mk), prefetch mask(t+1) ---
#pragma unroll
        for (int nb = 0; nb < 4; ++nb)
#pragma unroll
            for (int r = 0; r < 4; ++r) {
                float tt2 = __fmaf_rn(C1, sa[nb][r], C2);
                sa[nb][r] = __fmaf_rn(mk[nb][r], tt2, -C2);
            }
#pragma unroll
        for (int nb = 0; nb < 4; ++nb)
            mk[nb] = *(const f32x4*)(Mrow + keyn + nb * 16);

        // --- online softmax for q = q0+l15 (16 lane-local keys, 2 shfl) ---
        float vmax = -1e30f;
#pragma unroll
        for (int nb = 0; nb < 4; ++nb)
#pragma unroll
            for (int r = 0; r < 4; ++r)
                vmax = fmaxf(vmax, sa[nb][r]);
        vmax = fmaxf(vmax, __shfl_xor(vmax, 16));
        vmax = fmaxf(vmax, __shfl_xor(vmax, 32));

        // --- defer-rescale (T13): only rescale when max grew > 8 (log2) ---
        float alpha = 1.f;
        if (__any(vmax > mrun + 8.f)) {
            float mnew = fmaxf(mrun, vmax);
            alpha = fast_exp2(mrun - mnew);
            mrun = mnew;
            float a4[4];
#pragma unroll
            for (int r = 0; r < 4; ++r)
                a4[r] = __shfl(alpha, quad * 4 + r);
#pragma unroll
            for (int cb = 0; cb < 4; ++cb)
#pragma unroll
                for (int r = 0; r < 4; ++r)
                    oacc[cb][r] *= a4[r];
        }

        // --- P = exp2(s2 - m2); row sum ---
        float accs = 0.f;
#pragma unroll
        for (int nb = 0; nb < 4; ++nb)
#pragma unroll
            for (int r = 0; r < 4; ++r) {
                float p = fast_exp2(sa[nb][r] - mrun);
                sa[nb][r] = p;
                accs += p;
            }
        accs += __shfl_xor(accs, 16);
        accs += __shfl_xor(accs, 32);
        lrun = lrun * alpha + accs;

        // --- pack P -> Ps (swizzled, wave-private): 4 x 8B stores ---
#pragma unroll
        for (int nb = 0; nb < 4; ++nb) {
            union { __bf16 hh[4]; uint2 u; } pk;
            pk.hh[0] = (__bf16)sa[nb][0];
            pk.hh[1] = (__bf16)sa[nb][1];
            pk.hh[2] = (__bf16)sa[nb][2];
            pk.hh[3] = (__bf16)sa[nb][3];
            *(uint2*)(PsW + (((nb * 2 + (quad >> 1)) ^ swq) << 4) + (quad & 1) * 8) = pk.u;
        }
        asm volatile("s_waitcnt lgkmcnt(0)" ::: "memory");
        __builtin_amdgcn_sched_barrier(0);

        bf16x8 pf0 = *(const bf16x8*)(PsW + (((quad) ^ swq) << 4));
        bf16x8 pf1 = *(const bf16x8*)(PsW + (((4 + quad) ^ swq) << 4));

        // --- O += P V from Vt[cur] ---
        __builtin_amdgcn_s_setprio(1);
#pragma unroll
        for (int cb = 0; cb < 4; ++cb) {
            const char* vb = vcur + (cb * 16 + l15) * 128;
            bf16x8 vf0 = *(const bf16x8*)(vb + (((quad) ^ swq) << 4));
            bf16x8 vf1 = *(const bf16x8*)(vb + (((4 + quad) ^ swq) << 4));
            oacc[cb] = __builtin_amdgcn_mfma_f32_16x16x32_bf16(pf0, vf0, oacc[cb], 0, 0, 0);
            oacc[cb] = __builtin_amdgcn_mfma_f32_16x16x32_bf16(pf1, vf1, oacc[cb], 0, 0, 0);
        }
        __builtin_amdgcn_s_setprio(0);
    }

    // epilogue: l broadcast, bf16 Ao out
    float l4[4];
#pragma unroll
    for (int r = 0; r < 4; ++r)
        l4[r] = __shfl(lrun, quad * 4 + r);
#pragma unroll
    for (int cb = 0; cb < 4; ++cb) {
#pragma unroll
        for (int r = 0; r < 4; ++r) {
            int qq = q0 + quad * 4 + r;
            float v = oacc[cb][r] / l4[r];
            Out[((size_t)(b * SEQ + qq)) * DMODEL + h * 64 + cb * 16 + l15] = (__bf16)v;
        }
    }
}

// ---------------------------------------------------------------------------
extern "C" void kernel_launch(void* const* d_in, const int* in_sizes, int n_in,
                              void* d_out, int out_size, void* d_ws, size_t ws_size,
                              hipStream_t stream)
{
    const float* src  = nullptr;  // 4194304
    const float* mask = nullptr;  // 8388608
    const float* Wqkv = nullptr;  // 3145728
    const float* bqkv = nullptr;  // 3072
    const float* Wout = nullptr;  // 1048576
    const float* bout = nullptr;  // 1024
    for (int i = 0; i < n_in; ++i) {
        switch (in_sizes[i]) {
            case 4194304: src  = (const float*)d_in[i]; break;
            case 8388608: mask = (const float*)d_in[i]; break;
            case 3145728: Wqkv = (const float*)d_in[i]; break;
            case 3072:    bqkv = (const float*)d_in[i]; break;
            case 1048576: Wout = (const float*)d_in[i]; break;
            case 1024:    bout = (const float*)d_in[i]; break;
        }
    }
    float* out = (float*)d_out;                  // [2,2048,1024] fp32

    const size_t NE = (size_t)2 * 16 * SEQ * 64; // 4M elems
    __bf16* Qb     = (__bf16*)d_ws;              // 4M
    __bf16* Kb     = Qb + NE;                    // 4M
    __bf16* Vtg    = Kb + NE;                    // 4M  [bh][64][SEQ] (direct V^T)
    __bf16* SrcBf  = Vtg + NE;                   // 4M  (dead after GEMM1)
    __bf16* Wqkv_t = SrcBf + NE;                 // 3M  [3072][1024]
    __bf16* Wout_t = Wqkv_t + (size_t)3072 * 1024; // 1M [1024][1024]
    __bf16* Ao     = SrcBf;                      // alias: SrcBf dead by then
    // total: 4+4+4+4+3+1 = 20M bf16 = 40MB

    // prep: both weight transposes + src convert, ONE launch
    prep_kernel<<<dim3(6144), 256, 0, stream>>>(src, Wqkv, Wout,
                                                SrcBf, Wqkv_t, Wout_t);

    // GEMM1: src_bf16 @ Wqkv -> scatter Q/K + direct V^T (transpose_v fused)
    gemm_kernel<128, 128><<<dim3(3072 / 128, 4096 / 128), 256, 0, stream>>>(
        SrcBf, Wqkv_t, bqkv, Qb, Kb, Vtg, nullptr, 1024, 3072, 0);

    // attention: 1024 blocks of 256 threads (4 waves, 16 q each)
    attn_kernel<<<dim3(32, SEQ / 64), 256, 0, stream>>>(Qb, Kb, Vtg, mask, Ao);

    // GEMM2: Ao(bf16) @ Wout + b -> out (fp32)  (64x128, 512 blocks = 2/CU)
    gemm_kernel<64, 128><<<dim3(1024 / 128, 4096 / 64), 256, 0, stream>>>(
        Ao, Wout_t, bout, nullptr, nullptr, nullptr, out, 1024, 1024, 1);
}

// Round 14
// 244.294 us; speedup vs baseline: 1.3169x; 1.3169x over previous
//
#include <hip/hip_runtime.h>
#include <stdint.h>

// Problem: B=2, S=2048, D=1024, H=16, dh=64
// Inputs fp32, OUTPUT fp32. Internals bf16 (threshold has bf16 floor).
#define SEQ    2048
#define DMODEL 1024

typedef __bf16 bf16x8 __attribute__((ext_vector_type(8)));
typedef float  f32x4  __attribute__((ext_vector_type(4)));

typedef __attribute__((address_space(1))) const void CGV;  // global
typedef __attribute__((address_space(3))) void LDSV;       // LDS

__device__ __forceinline__ void load_lds16(const void* g, void* l) {
    __builtin_amdgcn_global_load_lds((CGV*)g, (LDSV*)l, 16, 0, 0);
}

// native v_exp_f32 (llvm.exp2.f32 is legal on amdgcn)
__device__ __forceinline__ float fast_exp2(float x) { return __builtin_exp2f(x); }

// ---------------------------------------------------------------------------
// prep_kernel: fuses {Wqkv transpose, Wout transpose, src f32->bf16 convert}
// into ONE launch.  blocks [0,3072): Wqkv; [3072,4096): Wout; [4096,6144): src.
// ---------------------------------------------------------------------------
__global__ __launch_bounds__(256)
void prep_kernel(const float* __restrict__ src, const float* __restrict__ Wqkv,
                 const float* __restrict__ Wout, __bf16* __restrict__ SrcBf,
                 __bf16* __restrict__ Wqkv_t, __bf16* __restrict__ Wout_t)
{
    __shared__ float tile[32][33];
    const int id = blockIdx.x;
    const int t  = threadIdx.x;
    if (id < 4096) {
        const float* in;
        __bf16* out;
        int R, C, bx, by;
        if (id < 3072) { in = Wqkv; out = Wqkv_t; R = 1024; C = 3072; bx = id % 96; by = id / 96; }
        else           { int l = id - 3072; in = Wout; out = Wout_t; R = 1024; C = 1024; bx = l & 31; by = l >> 5; }
        const int tx = t & 31, ty = t >> 5;
        const int c0 = bx * 32, r0 = by * 32;
#pragma unroll
        for (int i = 0; i < 4; ++i)
            tile[ty + i * 8][tx] = in[(size_t)(r0 + ty + i * 8) * C + c0 + tx];
        __syncthreads();
#pragma unroll
        for (int i = 0; i < 4; ++i)
            out[(size_t)(c0 + ty + i * 8) * R + r0 + tx] = (__bf16)tile[tx][ty + i * 8];
    } else {
        const int i = ((id - 4096) * 256 + t) * 8;
        float4 a = *(const float4*)(src + i);
        float4 b = *(const float4*)(src + i + 4);
        __bf16 tmp[8] = { (__bf16)a.x, (__bf16)a.y, (__bf16)a.z, (__bf16)a.w,
                          (__bf16)b.x, (__bf16)b.y, (__bf16)b.z, (__bf16)b.w };
        *(uint4*)(SrcBf + i) = *(uint4*)tmp;
    }
}

// ---------------------------------------------------------------------------
// GEMM v12 (verified): m97 structure + depth-2 pipeline + fused V^T store.
//   mode 0: Q/K scatter bf16 into [B,H,S,dh]; V written DIRECTLY TRANSPOSED
//           into Vtg [bh][dh][SEQ] as packed 8B stores.
//   mode 1: fp32 row-major store.
// ---------------------------------------------------------------------------
template<int BM, int BN>
__global__ __launch_bounds__(256)
void gemm_kernel(const __bf16* __restrict__ A, const __bf16* __restrict__ Bt,
                 const float* __restrict__ bias,
                 __bf16* __restrict__ Cq, __bf16* __restrict__ Ck,
                 __bf16* __restrict__ Cvt, float* __restrict__ Cplain,
                 int K, int N, int mode)
{
    __shared__ __attribute__((aligned(16))) __bf16 As[3][BM][32];
    __shared__ __attribute__((aligned(16))) __bf16 Bs[3][BN][32];

    const int t    = threadIdx.x;
    const int wave = __builtin_amdgcn_readfirstlane(t >> 6);
    const int lane = t & 63;
    const int l15  = lane & 15;
    const int quad = lane >> 4;
    const int wm   = (wave >> 1) * (BM / 2);
    const int wn   = (wave & 1) * (BN / 2);
    const int m0   = blockIdx.y * BM;
    const int n0   = blockIdx.x * BN;

    const int arow  = lane >> 2;        // 0..15 within a 16-row slab
    const int akoff = (lane & 3) * 8;   // lane covers 8 bf16 of k

    constexpr int MI  = BM / 32;        // 16-row blocks per wave (M)
    constexpr int NI  = BN / 32;        // 16-col blocks per wave (N)
    constexpr int NLD = BM / 64 + BN / 64;  // gll per wave per stage

    f32x4 acc[MI][NI] = {};

#define GSTAGE(buf, kk)                                                        \
    {                                                                          \
        _Pragma("unroll")                                                      \
        for (int p = 0; p < BM / 64; ++p) {                                    \
            int slab = (wave * (BM / 64) + p) * 16;                            \
            load_lds16(A  + (size_t)(m0 + slab + arow) * K + (kk) + akoff,     \
                       &As[buf][slab][0]);                                     \
        }                                                                      \
        _Pragma("unroll")                                                      \
        for (int p = 0; p < BN / 64; ++p) {                                    \
            int slab = (wave * (BN / 64) + p) * 16;                            \
            load_lds16(Bt + (size_t)(n0 + slab + arow) * K + (kk) + akoff,     \
                       &Bs[buf][slab][0]);                                     \
        }                                                                      \
    }

    // prologue: two stages in flight
    GSTAGE(0, 0);
    GSTAGE(1, 32);
    int cur = 0;
#pragma unroll 2
    for (int k0 = 0; k0 < K; k0 += 32) {
        // drain ONLY the oldest stage; the next stage rides (T4 counted wait).
        if (k0 + 64 < K) {
            if constexpr (NLD == 4) asm volatile("s_waitcnt vmcnt(4)" ::: "memory");
            else                    asm volatile("s_waitcnt vmcnt(3)" ::: "memory");
        } else {
            asm volatile("s_waitcnt vmcnt(0)" ::: "memory");   // tail
        }
        __builtin_amdgcn_s_barrier();
        __builtin_amdgcn_sched_barrier(0);
        if (k0 + 64 < K) {
            int c2 = cur + 2; if (c2 >= 3) c2 -= 3;
            GSTAGE(c2, k0 + 64);
        }
        __builtin_amdgcn_sched_barrier(0);

        bf16x8 af[MI], bfr[NI];
#pragma unroll
        for (int mi = 0; mi < MI; ++mi)
            af[mi] = *(const bf16x8*)(&As[cur][wm + mi * 16 + l15][quad * 8]);
#pragma unroll
        for (int ni = 0; ni < NI; ++ni)
            bfr[ni] = *(const bf16x8*)(&Bs[cur][wn + ni * 16 + l15][quad * 8]);
#pragma unroll
        for (int mi = 0; mi < MI; ++mi)
#pragma unroll
            for (int ni = 0; ni < NI; ++ni)
                acc[mi][ni] = __builtin_amdgcn_mfma_f32_16x16x32_bf16(
                    af[mi], bfr[ni], acc[mi][ni], 0, 0, 0);
        ++cur; if (cur == 3) cur = 0;
    }
#undef GSTAGE

    // epilogue: C/D layout col=lane&15, row=quad*4+reg
#pragma unroll
    for (int mi = 0; mi < MI; ++mi) {
        int rowb = m0 + wm + mi * 16 + quad * 4;
#pragma unroll
        for (int ni = 0; ni < NI; ++ni) {
            int col = n0 + wn + ni * 16 + l15;
            float bia = bias[col];
            float v4[4];
#pragma unroll
            for (int r = 0; r < 4; ++r)
                v4[r] = acc[mi][ni][r] + bia;
            if (mode == 0) {
                int part = col >> 10;        // wave-uniform per (ni)
                int rem  = col & 1023;
                int h = rem >> 6;
                int d = rem & 63;
                int b  = rowb >> 11;         // constant across r (rowb mult of 4)
                int sb = rowb & 2047;
                if (part == 2) {
                    // V^T fused: 4 consecutive s at fixed d -> one 8B store
                    union { __bf16 hh[4]; uint2 u; } pk;
                    pk.hh[0] = (__bf16)v4[0];
                    pk.hh[1] = (__bf16)v4[1];
                    pk.hh[2] = (__bf16)v4[2];
                    pk.hh[3] = (__bf16)v4[3];
                    *(uint2*)(Cvt + ((size_t)(b * 16 + h) * 64 + d) * SEQ + sb) = pk.u;
                } else {
                    __bf16* dst = (part == 0) ? Cq : Ck;
#pragma unroll
                    for (int r = 0; r < 4; ++r)
                        dst[(((size_t)(b * 16 + h)) * SEQ + sb + r) * 64 + d] = (__bf16)v4[r];
                }
            } else {
#pragma unroll
                for (int r = 0; r < 4; ++r)
                    Cplain[(size_t)(rowb + r) * N + col] = v4[r];   // fp32 output
            }
        }
    }
}

// ---------------------------------------------------------------------------
// MFMA flash attention v9 (verified best, ~102us — REVERTED from v13):
// v5 pipeline (16 q/wave, 4-wave blocks, gll K/V dbuf, one barrier+vmcnt(0)
// per tile, both-sides XOR swizzle) + exp2-domain softmax + defer-rescale.
// LDS 40960 (3 blocks/CU) is the measured local optimum: 5 blocks/CU (v13)
// thrashes L2 (+113MB FETCH, 1.7x slower); fewer waves (v6-v8) flat-to-worse.
// grid (B*H=32, S/64=32) x 256 thr.
// ---------------------------------------------------------------------------
__global__ __launch_bounds__(256, 4)
void attn_kernel(const __bf16* __restrict__ Q, const __bf16* __restrict__ Kb,
                 const __bf16* __restrict__ Vtg, const float* __restrict__ mask,
                 __bf16* __restrict__ Out)
{
    __shared__ __attribute__((aligned(16))) __bf16 Kt[2][64 * 64]; // [key][d] swz
    __shared__ __attribute__((aligned(16))) __bf16 Vt[2][64 * 64]; // [d][key] swz
    __shared__ __attribute__((aligned(16))) __bf16 Ps[4][16 * 64]; // [q][key] swz

    const int t    = threadIdx.x;
    const int wave = __builtin_amdgcn_readfirstlane(t >> 6);
    const int lane = t & 63;
    const int l15  = lane & 15;
    const int quad = lane >> 4;
    const int swq  = lane & 7;                  // == l15 & 7
    const int bh   = blockIdx.x;
    const int b    = bh >> 4;
    const int h    = bh & 15;
    const int q0   = blockIdx.y * 64 + wave * 16;

    const float C1 = 0.180336880f;    // 0.125 * log2(e)
    const float C2 = 14426.9502f;     // 1e4  * log2(e)

    const __bf16* Qp  = Q   + (size_t)bh * SEQ * 64;
    const __bf16* Kp  = Kb  + (size_t)bh * SEQ * 64;
    const __bf16* Vtp = Vtg + (size_t)bh * 64 * SEQ;   // [d][s]
    const float*  Mrow = mask + (size_t)b * SEQ * SEQ + (size_t)(q0 + l15) * SEQ + quad * 4;

    // ---- stage-source lane constants (v5-verified swizzle family) ----
    const int ch  = wave * 2;
    const int rw0 = ch * 8 + (lane >> 3);
    const int swz = ((lane & 7) ^ (lane >> 3)) * 8;
    const __bf16* kS0 = Kp  + (size_t)rw0 * 64 + swz;
    const __bf16* kS1 = Kp  + (size_t)(rw0 + 8) * 64 + swz;
    const __bf16* vS0 = Vtp + (size_t)rw0 * SEQ + swz;
    const __bf16* vS1 = Vtp + (size_t)(rw0 + 8) * SEQ + swz;

    bf16x8 qf[2];
#pragma unroll
    for (int ks = 0; ks < 2; ++ks)
        qf[ks] = *(const bf16x8*)(Qp + (size_t)(q0 + l15) * 64 + ks * 32 + quad * 8);

    f32x4 oacc[4] = {};
    float mrun = -1e30f, lrun = 0.f;   // scalar state: this lane's q = q0+l15

    // ---- prologue: stage tile 0 into buf0, mask tile 0 into regs ----
    load_lds16(kS0, &Kt[0][ch * 512]);
    load_lds16(kS1, &Kt[0][(ch + 1) * 512]);
    load_lds16(vS0, &Vt[0][ch * 512]);
    load_lds16(vS1, &Vt[0][(ch + 1) * 512]);
    f32x4 mk[4];
#pragma unroll
    for (int nb = 0; nb < 4; ++nb)
        mk[nb] = *(const f32x4*)(Mrow + nb * 16);

    const char* PsW = (const char*)&Ps[wave][0] + l15 * 128;

#pragma unroll 2
    for (int tt = 0; tt < SEQ / 64; ++tt) {
        const int key0 = tt * 64;
        const int keyn = (key0 + 64 <= SEQ - 64) ? key0 + 64 : SEQ - 64; // clamp
        const int cur  = tt & 1;
        const char* kcur = (const char*)&Kt[cur][0];
        const char* vcur = (const char*)&Vt[cur][0];
        __bf16* knxt = &Kt[cur ^ 1][0];
        __bf16* vnxt = &Vt[cur ^ 1][0];

        // --- top-of-tile: loads staged last tile are done; publish buffers ---
        asm volatile("s_waitcnt vmcnt(0)" ::: "memory");
        __builtin_amdgcn_s_barrier();
        __builtin_amdgcn_sched_barrier(0);

        // --- issue stage of tile t+1 (async; drained at NEXT tile's top) ---
        load_lds16(kS0 + (size_t)keyn * 64, knxt + ch * 512);
        load_lds16(kS1 + (size_t)keyn * 64, knxt + (ch + 1) * 512);
        load_lds16(vS0 + keyn, vnxt + ch * 512);
        load_lds16(vS1 + keyn, vnxt + (ch + 1) * 512);
        __builtin_amdgcn_sched_barrier(0);

        // --- QK from LDS K[cur] (S^T: rows=keys on l15, q via qf) ---
        f32x4 sa[4];
#pragma unroll
        for (int nb = 0; nb < 4; ++nb) {
            const char* kb = kcur + (nb * 16 + l15) * 128;
            bf16x8 kf0 = *(const bf16x8*)(kb + (((quad) ^ swq) << 4));
            bf16x8 kf1 = *(const bf16x8*)(kb + (((4 + quad) ^ swq) << 4));
            f32x4 z = {};
            z = __builtin_amdgcn_mfma_f32_16x16x32_bf16(kf0, qf[0], z, 0, 0, 0);
            z = __builtin_amdgcn_mfma_f32_16x16x32_bf16(kf1, qf[1], z, 0, 0, 0);
            sa[nb] = z;
        }

        // --- mask + scale in log2 domain (consume mk), prefetch mask(t+1) ---
#pragma unroll
        for (int nb = 0; nb < 4; ++nb)
#pragma unroll
            for (int r = 0; r < 4; ++r) {
                float tt2 = __fmaf_rn(C1, sa[nb][r], C2);
                sa[nb][r] = __fmaf_rn(mk[nb][r], tt2, -C2);
            }
#pragma unroll
        for (int nb = 0; nb < 4; ++nb)
            mk[nb] = *(const f32x4*)(Mrow + keyn + nb * 16);

        // --- online softmax for q = q0+l15 (16 lane-local keys, 2 shfl) ---
        float vmax = -1e30f;
#pragma unroll
        for (int nb = 0; nb < 4; ++nb)
#pragma unroll
            for (int r = 0; r < 4; ++r)
                vmax = fmaxf(vmax, sa[nb][r]);
        vmax = fmaxf(vmax, __shfl_xor(vmax, 16));
        vmax = fmaxf(vmax, __shfl_xor(vmax, 32));

        // --- defer-rescale (T13): only rescale when max grew > 8 (log2) ---
        float alpha = 1.f;
        if (__any(vmax > mrun + 8.f)) {
            float mnew = fmaxf(mrun, vmax);
            alpha = fast_exp2(mrun - mnew);
            mrun = mnew;
            float a4[4];
#pragma unroll
            for (int r = 0; r < 4; ++r)
                a4[r] = __shfl(alpha, quad * 4 + r);
#pragma unroll
            for (int cb = 0; cb < 4; ++cb)
#pragma unroll
                for (int r = 0; r < 4; ++r)
                    oacc[cb][r] *= a4[r];
        }

        // --- P = exp2(s2 - m2); row sum ---
        float accs = 0.f;
#pragma unroll
        for (int nb = 0; nb < 4; ++nb)
#pragma unroll
            for (int r = 0; r < 4; ++r) {
                float p = fast_exp2(sa[nb][r] - mrun);
                sa[nb][r] = p;
                accs += p;
            }
        accs += __shfl_xor(accs, 16);
        accs += __shfl_xor(accs, 32);
        lrun = lrun * alpha + accs;

        // --- pack P -> Ps (swizzled, wave-private): 4 x 8B stores ---
#pragma unroll
        for (int nb = 0; nb < 4; ++nb) {
            union { __bf16 hh[4]; uint2 u; } pk;
            pk.hh[0] = (__bf16)sa[nb][0];
            pk.hh[1] = (__bf16)sa[nb][1];
            pk.hh[2] = (__bf16)sa[nb][2];
            pk.hh[3] = (__bf16)sa[nb][3];
            *(uint2*)(PsW + (((nb * 2 + (quad >> 1)) ^ swq) << 4) + (quad & 1) * 8) = pk.u;
        }
        asm volatile("s_waitcnt lgkmcnt(0)" ::: "memory");
        __builtin_amdgcn_sched_barrier(0);

        bf16x8 pf0 = *(const bf16x8*)(PsW + (((quad) ^ swq) << 4));
        bf16x8 pf1 = *(const bf16x8*)(PsW + (((4 + quad) ^ swq) << 4));

        // --- O += P V from LDS V[cur] ---
        __builtin_amdgcn_s_setprio(1);
#pragma unroll
        for (int cb = 0; cb < 4; ++cb) {
            const char* vb = vcur + (cb * 16 + l15) * 128;
            bf16x8 vf0 = *(const bf16x8*)(vb + (((quad) ^ swq) << 4));
            bf16x8 vf1 = *(const bf16x8*)(vb + (((4 + quad) ^ swq) << 4));
            oacc[cb] = __builtin_amdgcn_mfma_f32_16x16x32_bf16(pf0, vf0, oacc[cb], 0, 0, 0);
            oacc[cb] = __builtin_amdgcn_mfma_f32_16x16x32_bf16(pf1, vf1, oacc[cb], 0, 0, 0);
        }
        __builtin_amdgcn_s_setprio(0);
    }

    // epilogue: l broadcast, bf16 Ao out
    float l4[4];
#pragma unroll
    for (int r = 0; r < 4; ++r)
        l4[r] = __shfl(lrun, quad * 4 + r);
#pragma unroll
    for (int cb = 0; cb < 4; ++cb) {
#pragma unroll
        for (int r = 0; r < 4; ++r) {
            int qq = q0 + quad * 4 + r;
            float v = oacc[cb][r] / l4[r];
            Out[((size_t)(b * SEQ + qq)) * DMODEL + h * 64 + cb * 16 + l15] = (__bf16)v;
        }
    }
}

// ---------------------------------------------------------------------------
extern "C" void kernel_launch(void* const* d_in, const int* in_sizes, int n_in,
                              void* d_out, int out_size, void* d_ws, size_t ws_size,
                              hipStream_t stream)
{
    const float* src  = nullptr;  // 4194304
    const float* mask = nullptr;  // 8388608
    const float* Wqkv = nullptr;  // 3145728
    const float* bqkv = nullptr;  // 3072
    const float* Wout = nullptr;  // 1048576
    const float* bout = nullptr;  // 1024
    for (int i = 0; i < n_in; ++i) {
        switch (in_sizes[i]) {
            case 4194304: src  = (const float*)d_in[i]; break;
            case 8388608: mask = (const float*)d_in[i]; break;
            case 3145728: Wqkv = (const float*)d_in[i]; break;
            case 3072:    bqkv = (const float*)d_in[i]; break;
            case 1048576: Wout = (const float*)d_in[i]; break;
            case 1024:    bout = (const float*)d_in[i]; break;
        }
    }
    float* out = (float*)d_out;                  // [2,2048,1024] fp32

    const size_t NE = (size_t)2 * 16 * SEQ * 64; // 4M elems
    __bf16* Qb     = (__bf16*)d_ws;              // 4M
    __bf16* Kb     = Qb + NE;                    // 4M
    __bf16* Vtg    = Kb + NE;                    // 4M  [bh][64][SEQ] (direct V^T)
    __bf16* SrcBf  = Vtg + NE;                   // 4M  (dead after GEMM1)
    __bf16* Wqkv_t = SrcBf + NE;                 // 3M  [3072][1024]
    __bf16* Wout_t = Wqkv_t + (size_t)3072 * 1024; // 1M [1024][1024]
    __bf16* Ao     = SrcBf;                      // alias: SrcBf dead by then
    // total: 4+4+4+4+3+1 = 20M bf16 = 40MB

    // prep: both weight transposes + src convert, ONE launch
    prep_kernel<<<dim3(6144), 256, 0, stream>>>(src, Wqkv, Wout,
                                                SrcBf, Wqkv_t, Wout_t);

    // GEMM1: src_bf16 @ Wqkv -> scatter Q/K + direct V^T (transpose_v fused)
    gemm_kernel<128, 128><<<dim3(3072 / 128, 4096 / 128), 256, 0, stream>>>(
        SrcBf, Wqkv_t, bqkv, Qb, Kb, Vtg, nullptr, 1024, 3072, 0);

    // attention: 1024 blocks of 256 threads (4 waves, 16 q each)
    attn_kernel<<<dim3(32, SEQ / 64), 256, 0, stream>>>(Qb, Kb, Vtg, mask, Ao);

    // GEMM2: Ao(bf16) @ Wout + b -> out (fp32)  (64x128, 512 blocks = 2/CU)
    gemm_kernel<64, 128><<<dim3(1024 / 128, 4096 / 64), 256, 0, stream>>>(
        Ao, Wout_t, bout, nullptr, nullptr, nullptr, out, 1024, 1024, 1);
}